// Round 6
// baseline (120.987 us; speedup 1.0000x reference)
//
#include <hip/hip_runtime.h>
#include <math.h>

#define NCLASS 100
#define NSEG 30
#define F4_PER_ROW 25            // 100 floats = 25 float4, row-aligned
#define ROWS_PER_GRP 16
#define F4_PER_GRP (F4_PER_ROW * ROWS_PER_GRP)   // 400

__device__ __forceinline__ float e4(float4 v) {
    return __expf(v.x) + __expf(v.y) + __expf(v.z) + __expf(v.w);
}

// ---------------------------------------------------------------------------
// Kernel 1: fused CE partial sum + per-segment label histogram.
// Fully-coalesced loads: per group (16 rows = 400 float4 = 6400B contiguous),
// lane l loads float4 m = l + 64k (k=0..5; k=6 lanes 0..15) -> every dwordx4
// instruction is 1024B of consecutive memory (8 full cache lines).
// Row reduction via per-wave LDS bounce: part[m] = exp-partial of float4 m;
// row r's exp-sum = sum(part[25r .. 25r+24]) read back quad-per-row.
// Requires N % 16 == 0 (true: N = 2^20).
// Grid 2048 (8 blocks/CU): the ONLY change vs round 4 — isolate occupancy.
// ---------------------------------------------------------------------------
__global__ __launch_bounds__(256) void ce_hist_kernel(
    const float* __restrict__ logits,   // [N, 100]
    const int*   __restrict__ target,   // [N]
    const int*   __restrict__ seg,      // [N]
    int N,
    int*    __restrict__ g_counts,      // [NSEG*NCLASS]
    double* __restrict__ g_loss)        // [1]
{
    __shared__ int    lds_hist[NSEG * NCLASS];   // 12 KB
    __shared__ float  part[4][F4_PER_GRP];       // 6.4 KB (per-wave slices)
    __shared__ double lds_loss[4];

    for (int i = threadIdx.x; i < NSEG * NCLASS; i += blockDim.x) lds_hist[i] = 0;
    __syncthreads();

    const int lane          = threadIdx.x & 63;
    const int wv            = threadIdx.x >> 6;
    const int sub           = lane & 3;     // quad sub-index (pass 2)
    const int q             = lane >> 2;    // row within group (pass 2)
    const int wavesPerBlock = blockDim.x >> 6;
    const int gwave         = blockIdx.x * wavesPerBlock + wv;
    const int totWaves      = gridDim.x * wavesPerBlock;
    const int ngroups       = N >> 4;       // N % 16 == 0

    double acc = 0.0;

    for (int grp = gwave; grp < ngroups; grp += totWaves) {
        const int row = grp * ROWS_PER_GRP + q;

        // prefetch ids early (64B contiguous; quad lanes share the word)
        const int t = target[row];
        const int s = seg[row];

        // ---- pass 1: sequential 1024B-coalesced loads + exp partials ----
        const float4* g4 = (const float4*)logits + (size_t)grp * F4_PER_GRP;
        float4 f0 = g4[lane        ];
        float4 f1 = g4[lane + 64   ];
        float4 f2 = g4[lane + 128  ];
        float4 f3 = g4[lane + 192  ];
        float4 f4v= g4[lane + 256  ];
        float4 f5 = g4[lane + 320  ];

        part[wv][lane      ] = e4(f0);
        part[wv][lane + 64 ] = e4(f1);
        part[wv][lane + 128] = e4(f2);
        part[wv][lane + 192] = e4(f3);
        part[wv][lane + 256] = e4(f4v);
        part[wv][lane + 320] = e4(f5);
        if (lane < 16) {
            float4 f6 = g4[lane + 384];
            part[wv][lane + 384] = e4(f6);
        }
        // same-wave producer->consumer: lgkmcnt ordering, no barrier needed

        // ---- pass 2: quad-per-row gather of 25 partials ----
        const int base = F4_PER_ROW * q + sub;
        float e = part[wv][base     ] + part[wv][base + 4 ] + part[wv][base + 8 ]
                + part[wv][base + 12] + part[wv][base + 16] + part[wv][base + 20];
        if (sub == 0) e += part[wv][F4_PER_ROW * q + 24];
        e += __shfl_xor(e, 1);
        e += __shfl_xor(e, 2);

        // x[target]: L1/L2-hot gather (this CU just streamed those lines)
        const float xt = logits[(size_t)row * NCLASS + t];

        if (sub == 0) {
            acc += (double)(__logf(e) - xt);
            atomicAdd(&lds_hist[s * NCLASS + t], 1);
        }
    }

    // full-wave sum of acc (nonzero only on sub==0 lanes)
    #pragma unroll
    for (int off = 32; off; off >>= 1) acc += __shfl_xor(acc, off);
    if (lane == 0) lds_loss[wv] = acc;
    __syncthreads();                 // also fences LDS hist atomics

    if (threadIdx.x == 0) {
        double b = 0.0;
        for (int w = 0; w < wavesPerBlock; ++w) b += lds_loss[w];
        atomicAdd(g_loss, b);
    }
    for (int i = threadIdx.x; i < NSEG * NCLASS; i += blockDim.x) {
        int c = lds_hist[i];
        if (c) atomicAdd(&g_counts[i], c);
    }
}

// ---------------------------------------------------------------------------
// Kernel 2: parallel per-segment argmax + loss finalize.
// 8 threads per segment; packed key (count<<7)|(127-c): max-key == first-max
// (jnp.argmax tie rule: equal counts -> smaller class id wins).
// ---------------------------------------------------------------------------
__global__ void finalize_kernel(
    const int* __restrict__ g_counts,
    const double* __restrict__ g_loss,
    int N,
    int* __restrict__ g_mode,
    float* __restrict__ out_loss)
{
    const int t = threadIdx.x;        // 256 threads
    const int s = t >> 3;             // segment
    const int j = t & 7;
    if (s < NSEG) {
        int bestKey = -1;
        #pragma unroll
        for (int c = j; c < NCLASS; c += 8) {
            int v = g_counts[s * NCLASS + c];
            int key = (v << 7) | (127 - c);
            bestKey = max(bestKey, key);
        }
        bestKey = max(bestKey, __shfl_xor(bestKey, 1));
        bestKey = max(bestKey, __shfl_xor(bestKey, 2));
        bestKey = max(bestKey, __shfl_xor(bestKey, 4));
        if (j == 0) g_mode[s] = 127 - (bestKey & 127);
    }
    if (t == 0) out_loss[0] = (float)(g_loss[0] / (double)N);
}

// ---------------------------------------------------------------------------
// Kernel 3: relabeled[i] = mode[seg[i]] written as fp32
// ---------------------------------------------------------------------------
__global__ __launch_bounds__(256) void relabel_kernel(
    const int* __restrict__ seg,
    const int* __restrict__ g_mode,
    float* __restrict__ out,
    int N)
{
    __shared__ float mode_f[NSEG];
    for (int i = threadIdx.x; i < NSEG; i += blockDim.x)
        mode_f[i] = (float)g_mode[i];
    __syncthreads();

    int idx    = blockIdx.x * blockDim.x + threadIdx.x;
    int stride = gridDim.x * blockDim.x;
    for (int i = idx; i < N; i += stride)
        out[i] = mode_f[seg[i]];
}

// ---------------------------------------------------------------------------
extern "C" void kernel_launch(void* const* d_in, const int* in_sizes, int n_in,
                              void* d_out, int out_size, void* d_ws, size_t ws_size,
                              hipStream_t stream)
{
    const float* logits = (const float*)d_in[0];
    const int*   target = (const int*)d_in[1];
    const int*   seg    = (const int*)d_in[2];
    float* out = (float*)d_out;

    const int N = in_sizes[1];          // N_PIXELS (2^20, divisible by 16)

    // workspace: [0..7] double loss_sum, [16..] counts[3000], then mode[30]
    double* g_loss   = (double*)d_ws;
    int*    g_counts = (int*)((char*)d_ws + 16);
    int*    g_mode   = (int*)((char*)d_ws + 16 + NSEG * NCLASS * sizeof(int));

    hipMemsetAsync(d_ws, 0, 16 + NSEG * NCLASS * sizeof(int), stream);

    ce_hist_kernel<<<2048, 256, 0, stream>>>(logits, target, seg, N, g_counts, g_loss);
    finalize_kernel<<<1, 256, 0, stream>>>(g_counts, g_loss, N, g_mode, out);
    relabel_kernel<<<1024, 256, 0, stream>>>(seg, g_mode, out + 1, N);
}

// Round 7
// 99.737 us; speedup vs baseline: 1.2131x; 1.2131x over previous
//
#include <hip/hip_runtime.h>
#include <math.h>

#define NCLASS 100
#define NSEG 30
#define NREP 8                   // replicated global count arrays (contention)
#define F4_PER_ROW 25            // 100 floats = 25 float4, row-aligned
#define ROWS_PER_GRP 16
#define F4_PER_GRP (F4_PER_ROW * ROWS_PER_GRP)   // 400

__device__ __forceinline__ float e4(float4 v) {
    return __expf(v.x) + __expf(v.y) + __expf(v.z) + __expf(v.w);
}

// ---------------------------------------------------------------------------
// Kernel 1: fused CE partial sum + per-segment label histogram.
// Fully-coalesced loads (1024B per instr) + per-wave LDS bounce for the row
// reduction (structure of round 4 = best so far). Flush now goes to one of
// NREP replicated count arrays (blockIdx&7) to cut same-address atomic
// serialization in the tail 8x.
// ---------------------------------------------------------------------------
__global__ __launch_bounds__(256) void ce_hist_kernel(
    const float* __restrict__ logits,   // [N, 100]
    const int*   __restrict__ target,   // [N]
    const int*   __restrict__ seg,      // [N]
    int N,
    int*    __restrict__ g_counts,      // [NREP][NSEG*NCLASS]
    double* __restrict__ g_loss)        // [1]
{
    __shared__ int    lds_hist[NSEG * NCLASS];   // 12 KB
    __shared__ float  part[4][F4_PER_GRP];       // 6.4 KB (per-wave slices)
    __shared__ double lds_loss[4];

    for (int i = threadIdx.x; i < NSEG * NCLASS; i += blockDim.x) lds_hist[i] = 0;
    __syncthreads();

    const int lane          = threadIdx.x & 63;
    const int wv            = threadIdx.x >> 6;
    const int sub           = lane & 3;     // quad sub-index (pass 2)
    const int q             = lane >> 2;    // row within group (pass 2)
    const int wavesPerBlock = blockDim.x >> 6;
    const int gwave         = blockIdx.x * wavesPerBlock + wv;
    const int totWaves      = gridDim.x * wavesPerBlock;
    const int ngroups       = N >> 4;       // N % 16 == 0

    double acc = 0.0;

    for (int grp = gwave; grp < ngroups; grp += totWaves) {
        const int row = grp * ROWS_PER_GRP + q;

        // prefetch ids early (64B contiguous; quad lanes share the word)
        const int t = target[row];
        const int s = seg[row];

        // ---- pass 1: sequential 1024B-coalesced loads + exp partials ----
        const float4* g4 = (const float4*)logits + (size_t)grp * F4_PER_GRP;
        float4 f0 = g4[lane        ];
        float4 f1 = g4[lane + 64   ];
        float4 f2 = g4[lane + 128  ];
        float4 f3 = g4[lane + 192  ];
        float4 f4v= g4[lane + 256  ];
        float4 f5 = g4[lane + 320  ];

        part[wv][lane      ] = e4(f0);
        part[wv][lane + 64 ] = e4(f1);
        part[wv][lane + 128] = e4(f2);
        part[wv][lane + 192] = e4(f3);
        part[wv][lane + 256] = e4(f4v);
        part[wv][lane + 320] = e4(f5);
        if (lane < 16) {
            float4 f6 = g4[lane + 384];
            part[wv][lane + 384] = e4(f6);
        }
        // same-wave producer->consumer: lgkmcnt ordering, no barrier needed

        // ---- pass 2: quad-per-row gather of 25 partials ----
        const int base = F4_PER_ROW * q + sub;
        float e = part[wv][base     ] + part[wv][base + 4 ] + part[wv][base + 8 ]
                + part[wv][base + 12] + part[wv][base + 16] + part[wv][base + 20];
        if (sub == 0) e += part[wv][F4_PER_ROW * q + 24];
        e += __shfl_xor(e, 1);
        e += __shfl_xor(e, 2);

        // x[target]: L1/L2-hot gather (this CU just streamed those lines)
        const float xt = logits[(size_t)row * NCLASS + t];

        if (sub == 0) {
            acc += (double)(__logf(e) - xt);
            atomicAdd(&lds_hist[s * NCLASS + t], 1);
        }
    }

    // full-wave sum of acc (nonzero only on sub==0 lanes)
    #pragma unroll
    for (int off = 32; off; off >>= 1) acc += __shfl_xor(acc, off);
    if (lane == 0) lds_loss[wv] = acc;
    __syncthreads();                 // also fences LDS hist atomics

    if (threadIdx.x == 0) {
        double b = 0.0;
        for (int w = 0; w < wavesPerBlock; ++w) b += lds_loss[w];
        atomicAdd(g_loss, b);
    }
    int* my_counts = g_counts + (blockIdx.x & (NREP - 1)) * (NSEG * NCLASS);
    for (int i = threadIdx.x; i < NSEG * NCLASS; i += blockDim.x) {
        int c = lds_hist[i];
        if (c) atomicAdd(&my_counts[i], c);
    }
}

// ---------------------------------------------------------------------------
// Kernel 2: parallel per-segment argmax over NREP replicas + loss finalize.
// 8 threads per segment; packed key (count<<7)|(127-c): max-key == first-max
// (jnp.argmax tie rule: equal counts -> smaller class id wins).
// ---------------------------------------------------------------------------
__global__ void finalize_kernel(
    const int* __restrict__ g_counts,
    const double* __restrict__ g_loss,
    int N,
    int* __restrict__ g_mode,
    float* __restrict__ out_loss)
{
    const int t = threadIdx.x;        // 256 threads
    const int s = t >> 3;             // segment
    const int j = t & 7;
    if (s < NSEG) {
        int bestKey = -1;
        for (int c = j; c < NCLASS; c += 8) {
            int v = 0;
            #pragma unroll
            for (int r = 0; r < NREP; ++r)          // independent loads -> ILP
                v += g_counts[r * (NSEG * NCLASS) + s * NCLASS + c];
            int key = (v << 7) | (127 - c);
            bestKey = max(bestKey, key);
        }
        bestKey = max(bestKey, __shfl_xor(bestKey, 1));
        bestKey = max(bestKey, __shfl_xor(bestKey, 2));
        bestKey = max(bestKey, __shfl_xor(bestKey, 4));
        if (j == 0) g_mode[s] = 127 - (bestKey & 127);
    }
    if (t == 0) out_loss[0] = (float)(g_loss[0] / (double)N);
}

// ---------------------------------------------------------------------------
// Kernel 3: relabeled[i] = mode[seg[i]] written as fp32
// ---------------------------------------------------------------------------
__global__ __launch_bounds__(256) void relabel_kernel(
    const int* __restrict__ seg,
    const int* __restrict__ g_mode,
    float* __restrict__ out,
    int N)
{
    __shared__ float mode_f[NSEG];
    for (int i = threadIdx.x; i < NSEG; i += blockDim.x)
        mode_f[i] = (float)g_mode[i];
    __syncthreads();

    int idx    = blockIdx.x * blockDim.x + threadIdx.x;
    int stride = gridDim.x * blockDim.x;
    for (int i = idx; i < N; i += stride)
        out[i] = mode_f[seg[i]];
}

// ---------------------------------------------------------------------------
extern "C" void kernel_launch(void* const* d_in, const int* in_sizes, int n_in,
                              void* d_out, int out_size, void* d_ws, size_t ws_size,
                              hipStream_t stream)
{
    const float* logits = (const float*)d_in[0];
    const int*   target = (const int*)d_in[1];
    const int*   seg    = (const int*)d_in[2];
    float* out = (float*)d_out;

    const int N = in_sizes[1];          // N_PIXELS (2^20, divisible by 16)

    // workspace: [0..7] double loss_sum, [16..] counts[NREP][3000], then mode[30]
    double* g_loss   = (double*)d_ws;
    int*    g_counts = (int*)((char*)d_ws + 16);
    int*    g_mode   = (int*)((char*)d_ws + 16 + (size_t)NREP * NSEG * NCLASS * sizeof(int));

    hipMemsetAsync(d_ws, 0, 16 + (size_t)NREP * NSEG * NCLASS * sizeof(int), stream);

    ce_hist_kernel<<<1024, 256, 0, stream>>>(logits, target, seg, N, g_counts, g_loss);
    finalize_kernel<<<1, 256, 0, stream>>>(g_counts, g_loss, N, g_mode, out);
    relabel_kernel<<<2048, 256, 0, stream>>>(seg, g_mode, out + 1, N);
}